// Round 1
// baseline (337.583 us; speedup 1.0000x reference)
//
#include <hip/hip_runtime.h>
#include <hip/hip_bf16.h>
#include <stdint.h>
#include <stddef.h>

typedef __bf16 bf16;
typedef bf16 bf16x8 __attribute__((ext_vector_type(8)));
typedef bf16 bf16x4 __attribute__((ext_vector_type(4)));
typedef float f32x4 __attribute__((ext_vector_type(4)));

#define N_ROWS 65536
#define EMB    1024
#define ATTD   512
#define KDIM   2048
#define BM     128
#define BK     64
#define NBLK   (N_ROWS / BM)   // 512

__device__ __forceinline__ void gload_lds16(const void* g, void* l) {
  __builtin_amdgcn_global_load_lds(
      (const __attribute__((address_space(1))) void*)g,
      (__attribute__((address_space(3))) void*)l, 16, 0, 0);
}

// ---------------------------------------------------------------------------
// K0: W1 [2048x512] f32 row-major  ->  W1t bf16 [n=512][k=2048], pre-swizzled
// within each 64-k tile so that linear global_load_lds deposits the swizzled
// layout: element (n, kb*64+kt) stored at  n*2048 + kb*64 + ((kt>>3)^(n&7))*8 + (kt&7)
// ---------------------------------------------------------------------------
__global__ __launch_bounds__(256) void k_prep_w1(const float* __restrict__ W1,
                                                 bf16* __restrict__ W1t) {
  __shared__ float tile[64][65];
  const int bx = blockIdx.x;   // k-tile 0..31
  const int by = blockIdx.y;   // n-tile 0..7
  const int t  = threadIdx.x;  // 0..255
  const int k0 = bx * 64, n0 = by * 64;

  const int kt = t >> 2, c4 = (t & 3) * 16;
  const float* src = W1 + (size_t)(k0 + kt) * ATTD + n0 + c4;
  #pragma unroll
  for (int q = 0; q < 4; q++) {
    float4 v = *(const float4*)(src + q * 4);
    tile[kt][c4 + q * 4 + 0] = v.x;
    tile[kt][c4 + q * 4 + 1] = v.y;
    tile[kt][c4 + q * 4 + 2] = v.z;
    tile[kt][c4 + q * 4 + 3] = v.w;
  }
  __syncthreads();

  const int nr = t >> 2;
  const int n_glob = n0 + nr;
  const size_t base = (size_t)n_glob * KDIM + k0;
  #pragma unroll
  for (int h = 0; h < 2; h++) {
    const int ktbase = c4 + h * 8;
    bf16x8 o;
    #pragma unroll
    for (int e = 0; e < 8; e++) o[e] = (bf16)tile[ktbase + e][nr];
    const int chunk = ((ktbase >> 3) ^ (n_glob & 7));
    *(bf16x8*)(W1t + base + chunk * 8) = o;
  }
}

// ---------------------------------------------------------------------------
// K1: fused GEMM + tanh-MLP score + per-block softmax stats.
// grid 512 blocks (128 rows each), 512 threads (8 waves: 2M x 4N).
// ---------------------------------------------------------------------------
__global__ __launch_bounds__(512) void k_gemm_score(
    const float* __restrict__ leaves, const float* __restrict__ anc,
    const bf16* __restrict__ W1t, const float* __restrict__ b1,
    const float* __restrict__ W2, const float* __restrict__ b2,
    float* __restrict__ scores, float* __restrict__ bmax,
    float* __restrict__ bsum) {
  __shared__ bf16 ldsA[BM * BK];    // 16 KiB, XOR-swizzled rows of 128B
  __shared__ bf16 ldsB[ATTD * BK];  // 64 KiB, swizzled via pre-swizzled source

  const int t    = threadIdx.x;
  const int lane = t & 63;
  const int wave = t >> 6;
  const int l15  = lane & 15;
  const int l4   = lane >> 4;
  const int wm   = wave >> 2;  // 0..1
  const int wn   = wave & 3;   // 0..3
  const int m0   = blockIdx.x * BM;

  const f32x4 zero4 = {0.f, 0.f, 0.f, 0.f};
  f32x4 acc[4][8];
  #pragma unroll
  for (int i = 0; i < 4; i++)
    #pragma unroll
    for (int j = 0; j < 8; j++) acc[i][j] = zero4;

  for (int kb = 0; kb < KDIM / BK; kb++) {
    // ---- stage A (f32 -> bf16, swizzled reg->LDS) ----
    const float* Abase = (kb < 16)
        ? (leaves + (size_t)m0 * EMB + (size_t)kb * BK)
        : (anc    + (size_t)m0 * EMB + (size_t)(kb - 16) * BK);
    #pragma unroll
    for (int s = 0; s < 4; s++) {
      const int i  = s * 512 + t;
      const int r  = i >> 4;
      const int c4 = i & 15;
      float4 v = *(const float4*)(Abase + (size_t)r * EMB + c4 * 4);
      bf16x4 o = {(bf16)v.x, (bf16)v.y, (bf16)v.z, (bf16)v.w};
      const int chunk = (c4 >> 1) ^ (r & 7);
      *(bf16x4*)(ldsA + r * BK + chunk * 8 + (c4 & 1) * 4) = o;
    }
    // ---- stage B (pre-swizzled source, linear LDS dest, 16B DMA) ----
    #pragma unroll
    for (int c = 0; c < 8; c++) {
      const int chunkid = (wave * 8 + c) * 64 + lane;  // 0..4095
      const int nr = chunkid >> 3;                     // 0..511
      const int cc = chunkid & 7;
      gload_lds16(W1t + (size_t)nr * KDIM + kb * BK + cc * 8,
                  ldsB + (wave * 8 + c) * 512);
    }
    __syncthreads();
    // ---- compute ----
    #pragma unroll
    for (int ks = 0; ks < 2; ks++) {
      bf16x8 afr[4];
      #pragma unroll
      for (int mi = 0; mi < 4; mi++) {
        const int row   = wm * 64 + mi * 16 + l15;
        const int chunk = (ks * 4 + l4) ^ (row & 7);
        afr[mi] = *(const bf16x8*)(ldsA + row * BK + chunk * 8);
      }
      #pragma unroll
      for (int ni = 0; ni < 8; ni++) {
        const int nrow  = wn * 128 + ni * 16 + l15;
        const int chunk = (ks * 4 + l4) ^ (nrow & 7);
        bf16x8 bfr = *(const bf16x8*)(ldsB + nrow * BK + chunk * 8);
        #pragma unroll
        for (int mi = 0; mi < 4; mi++)
          acc[mi][ni] = __builtin_amdgcn_mfma_f32_16x16x32_bf16(
              afr[mi], bfr, acc[mi][ni], 0, 0, 0);
      }
    }
    __syncthreads();
  }

  // ---- epilogue: score[r] = b2 + sum_col tanh(h + b1[col]) * W2[col] ----
  // acc[mi][ni][reg]: row = wm*64 + mi*16 + l4*4 + reg, col = wn*128 + ni*16 + l15
  float b1c[8], w2c[8];
  #pragma unroll
  for (int ni = 0; ni < 8; ni++) {
    const int col = wn * 128 + ni * 16 + l15;
    b1c[ni] = b1[col];
    w2c[ni] = W2[col];
  }
  float* sp   = (float*)ldsA;  // [4][128] partial scores (ldsA is dead now)
  float* redm = sp + 512;
  float* redz = sp + 520;
  #pragma unroll
  for (int mi = 0; mi < 4; mi++) {
    #pragma unroll
    for (int r = 0; r < 4; r++) {
      float p = 0.f;
      #pragma unroll
      for (int ni = 0; ni < 8; ni++)
        p += tanhf(acc[mi][ni][r] + b1c[ni]) * w2c[ni];
      p += __shfl_xor(p, 1);
      p += __shfl_xor(p, 2);
      p += __shfl_xor(p, 4);
      p += __shfl_xor(p, 8);
      if (l15 == 0) sp[wn * 128 + wm * 64 + mi * 16 + l4 * 4 + r] = p;
    }
  }
  __syncthreads();
  float myscore = 0.f;
  if (t < BM) {
    myscore = sp[t] + sp[128 + t] + sp[256 + t] + sp[384 + t] + b2[0];
    scores[m0 + t] = myscore;
  }
  // block max
  float mm = (t < BM) ? myscore : -3.0e38f;
  #pragma unroll
  for (int o = 32; o; o >>= 1) mm = fmaxf(mm, __shfl_xor(mm, o));
  if (lane == 0) redm[wave] = mm;
  __syncthreads();
  if (t == 0) {
    float g = redm[0];
    for (int i = 1; i < 8; i++) g = fmaxf(g, redm[i]);
    redm[0] = g;
  }
  __syncthreads();
  const float bM = redm[0];
  float ee = (t < BM) ? __expf(myscore - bM) : 0.f;
  #pragma unroll
  for (int o = 32; o; o >>= 1) ee += __shfl_xor(ee, o);
  if (lane == 0) redz[wave] = ee;
  __syncthreads();
  if (t == 0) {
    float z = 0.f;
    for (int i = 0; i < 8; i++) z += redz[i];
    bmax[blockIdx.x] = bM;
    bsum[blockIdx.x] = z;
  }
}

// ---------------------------------------------------------------------------
// K2: reduce 512 per-block (max, sumexp) pairs -> global M, Z
// ---------------------------------------------------------------------------
__global__ __launch_bounds__(512) void k_mz(const float* __restrict__ bmax,
                                            const float* __restrict__ bsum,
                                            float* __restrict__ MZ) {
  const int t = threadIdx.x, lane = t & 63, wave = t >> 6;
  __shared__ float rm[8], rs[8];
  const float m = bmax[t];
  float mm = m;
  #pragma unroll
  for (int o = 32; o; o >>= 1) mm = fmaxf(mm, __shfl_xor(mm, o));
  if (lane == 0) rm[wave] = mm;
  __syncthreads();
  if (t == 0) {
    float g = rm[0];
    for (int i = 1; i < 8; i++) g = fmaxf(g, rm[i]);
    rm[0] = g;
  }
  __syncthreads();
  const float M = rm[0];
  float z = bsum[t] * __expf(m - M);
  #pragma unroll
  for (int o = 32; o; o >>= 1) z += __shfl_xor(z, o);
  if (lane == 0) rs[wave] = z;
  __syncthreads();
  if (t == 0) {
    float Z = 0.f;
    for (int i = 0; i < 8; i++) Z += rs[i];
    MZ[0] = M;
    MZ[1] = Z;
  }
}

// ---------------------------------------------------------------------------
// K3: per-block partial weighted sum of ancestors: part[b][j] = sum_i w_i*anc[i][j]
// ---------------------------------------------------------------------------
__global__ __launch_bounds__(256) void k_part(const float* __restrict__ anc,
                                              const float* __restrict__ scores,
                                              const float* __restrict__ MZ,
                                              float* __restrict__ part) {
  __shared__ float w[BM];
  const int b = blockIdx.x, t = threadIdx.x;
  const float M = MZ[0];
  if (t < BM) w[t] = __expf(scores[(size_t)b * BM + t] - M);
  __syncthreads();
  float4 a = {0.f, 0.f, 0.f, 0.f};
  const float4* src = (const float4*)(anc + (size_t)b * BM * EMB) + t;
  #pragma unroll 4
  for (int i = 0; i < BM; i++) {
    float4 v = src[i * (EMB / 4)];
    const float wi = w[i];
    a.x += wi * v.x;
    a.y += wi * v.y;
    a.z += wi * v.z;
    a.w += wi * v.w;
  }
  ((float4*)(part + (size_t)b * EMB))[t] = a;
}

// ---------------------------------------------------------------------------
// K4: out[j] = (sum_b part[b][j]) / Z
// ---------------------------------------------------------------------------
__global__ __launch_bounds__(256) void k_final(const float* __restrict__ part,
                                               const float* __restrict__ MZ,
                                               float* __restrict__ out) {
  const int j = blockIdx.x * 256 + threadIdx.x;
  float s0 = 0.f, s1 = 0.f, s2 = 0.f, s3 = 0.f;
  for (int b = 0; b < NBLK; b += 4) {
    s0 += part[(size_t)(b + 0) * EMB + j];
    s1 += part[(size_t)(b + 1) * EMB + j];
    s2 += part[(size_t)(b + 2) * EMB + j];
    s3 += part[(size_t)(b + 3) * EMB + j];
  }
  out[j] = (s0 + s1 + s2 + s3) / MZ[1];
}

extern "C" void kernel_launch(void* const* d_in, const int* in_sizes, int n_in,
                              void* d_out, int out_size, void* d_ws,
                              size_t ws_size, hipStream_t stream) {
  const float* leaves = (const float*)d_in[0];
  const float* anc    = (const float*)d_in[1];
  const float* W1     = (const float*)d_in[2];
  const float* b1     = (const float*)d_in[3];
  const float* W2     = (const float*)d_in[4];
  const float* b2     = (const float*)d_in[5];
  float* out = (float*)d_out;

  char* ws = (char*)d_ws;
  bf16*  W1t    = (bf16*)ws;                                  // 2 MiB
  float* scores = (float*)(ws + (1u << 21));                  // 256 KiB
  float* bmax   = (float*)(ws + (1u << 21) + (1u << 18));     // 2 KiB
  float* bsum   = bmax + NBLK;                                // 2 KiB
  float* MZ     = bsum + NBLK;                                // 8 B
  float* part   = (float*)(ws + (1u << 21) + (1u << 19));     // 2 MiB

  k_prep_w1<<<dim3(32, 8), 256, 0, stream>>>(W1, W1t);
  k_gemm_score<<<dim3(NBLK), 512, 0, stream>>>(leaves, anc, W1t, b1, W2, b2,
                                               scores, bmax, bsum);
  k_mz<<<dim3(1), 512, 0, stream>>>(bmax, bsum, MZ);
  k_part<<<dim3(NBLK), 256, 0, stream>>>(anc, scores, MZ, part);
  k_final<<<dim3(EMB / 256), 256, 0, stream>>>(part, MZ, out);
}